// Round 11
// baseline (111.344 us; speedup 1.0000x reference)
//
#include <hip/hip_runtime.h>
#include <hip/hip_bf16.h>

// CriticREM: out = relu(relu([state|action]W1^T+b1)W2^T+b2) @ Wc^T + bc
//   Wc = sum_h alpha_h * Wh[h], bc = sum_h alpha_h * bh[h]
// B=65536, IN=128, HID=256, NUM_HEADS=200, OUT=1
//
// R12: R11 + DOUBLE-BUFFERED xs + 2 barriers/tile (was 3).
//   R11 evidence: total 110.7 = ~87us of UNCONDITIONAL 256MiB ws-poison
//   fills (present even with d_ws untouched — Story A dead) + critic
//   ~20-24us + gaps. Critic internals: MFMA ~1.6us, x-stream 5.3us,
//   L2 preamble ~6us -> the rest is the 3-barrier/tile convoy with one
//   8-wave block/CU (all pipes idle at barriers, per R8 counters).
//   Change: stage tile t+1's x into xs[nxt] BETWEEN GEMM1 and epi1
//   (GEMM1's ds_read+MFMA hides the px vmcnt), so barrier B (h1s ready)
//   also covers xs[nxt] -> the loop-top staging barrier is eliminated.
//   WAR safety: xs[nxt] last read by GEMM1(t-1) before B(t-1) < C(t-1) <
//   stage(t). h1s written by epi1(t+1) after C(t) > GEMM2(t) reads.
//   sPart written after B(t+1) > out-reads(t). All single-buffered except
//   xs. LDS 71KB -> 1 block/CU (same residency as measured best).
//   Prep/frags/GEMM bodies byte-identical to R11.

#define B_TOTAL 65536
#define SDIM 96
#define ADIM 32
#define IN_F 128
#define HID 256
#define NHEADS 200
#define BM 64           // batch rows per tile
#define NTILES 4        // tiles per block (grid 256)
#define XS_PITCH 132    // 264B row stride = 66 dw == 2 mod 32: conflict-free class
#define H1_PITCH 260    // 520B row stride = 130 dw == 2 mod 32: measured 0 (R2)

typedef __bf16 bf16;
typedef __attribute__((ext_vector_type(4))) __bf16 bf16x4;
typedef __attribute__((ext_vector_type(8))) __bf16 bf16x8;
typedef __attribute__((ext_vector_type(4))) float f32x4;

// ---- single fused kernel: 512 threads (8 waves), persistent over 4 tiles ----
__global__ __launch_bounds__(512, 1) void critic_kernel(
        const float* __restrict__ state, const float* __restrict__ action,
        const float* __restrict__ alphas,
        const float* __restrict__ W1, const float* __restrict__ b1,
        const float* __restrict__ W2, const float* __restrict__ b2,
        const float* __restrict__ Wh, const float* __restrict__ bh,
        float* __restrict__ out) {

    __shared__ bf16 xs[2][BM * XS_PITCH];  // 2 x 16896 B, x tiles [batch][k]
    __shared__ bf16 h1s[BM * H1_PITCH];    // 33280 B, h1 tile [batch][hidden]
    __shared__ float sPart[8][BM];         // 2048 B
    __shared__ float wcs[2][HID];          // 2048 B, head-collapse halves
    __shared__ float bcs;

    const int tid  = threadIdx.x;
    const int wave = tid >> 6;      // 0..7
    const int lane = tid & 63;
    const int q    = lane >> 4;     // 0..3
    const int ln   = lane & 15;     // 0..15
    const int colw = wave * 32;     // this wave's 32-hidden-col slice
    const int brow0 = blockIdx.x * (BM * NTILES);

    // staging geometry (used by all stage/prefetch sites)
    const int c0_  = tid;           // chunk ids: tid and tid+512
    const int r0_  = c0_ >> 4,  cc0 = c0_ & 15;
    const int r1_  = (c0_ + 512) >> 4, cc1 = (c0_ + 512) & 15;

    // ---- x prefetch for tile 0 FIRST: HBM stream, longest latency ----
    float4 px[2][2];
    {
        const float* s0 = (cc0 < 12) ? (state  + (size_t)(brow0 + r0_) * SDIM + cc0 * 8)
                                     : (action + (size_t)(brow0 + r0_) * ADIM + (cc0 - 12) * 8);
        px[0][0] = ((const float4*)s0)[0];
        px[0][1] = ((const float4*)s0)[1];
        const float* s1 = (cc1 < 12) ? (state  + (size_t)(brow0 + r1_) * SDIM + cc1 * 8)
                                     : (action + (size_t)(brow0 + r1_) * ADIM + (cc1 - 12) * 8);
        px[1][0] = ((const float4*)s1)[0];
        px[1][1] = ((const float4*)s1)[1];
    }

    // ---- cheap in-kernel prep: head collapse, cooperative over 512 thr ----
    {
        const int j    = tid & 255;
        const int half = tid >> 8;
        const int h0   = half * 100;
        float a = 0.f;
        #pragma unroll 10
        for (int hh = 0; hh < 100; ++hh) {
            const int h = h0 + hh;
            a += alphas[h] * Wh[(size_t)h * HID + j];
        }
        wcs[half][j] = a;
    }
    if (tid < 64) {   // wave 0: bc = sum_h alphas[h]*bh[h]
        float p = 0.f;
        for (int h = tid; h < NHEADS; h += 64) p += alphas[h] * bh[h];
        #pragma unroll
        for (int s = 1; s < 64; s <<= 1) p += __shfl_xor(p, s, 64);
        if (tid == 0) bcs = p;
    }

    // ---- preamble: ALL weight fragments into registers, once per block ----
    bf16x8 w1f[4][2];   // 32 VGPR : W1[colw+nt*16+ln][ks*32+q*8 ..]
    #pragma unroll
    for (int ks = 0; ks < 4; ++ks)
        #pragma unroll
        for (int nt = 0; nt < 2; ++nt) {
            const float* p = &W1[(size_t)(colw + nt * 16 + ln) * IN_F + ks * 32 + q * 8];
            float4 lo = ((const float4*)p)[0];
            float4 hi = ((const float4*)p)[1];
            w1f[ks][nt] = (bf16x8){(bf16)lo.x, (bf16)lo.y, (bf16)lo.z, (bf16)lo.w,
                                   (bf16)hi.x, (bf16)hi.y, (bf16)hi.z, (bf16)hi.w};
        }

    bf16x8 w2f[8][2];   // 64 VGPR
    #pragma unroll
    for (int ks = 0; ks < 8; ++ks)
        #pragma unroll
        for (int nt = 0; nt < 2; ++nt) {
            const float* p = &W2[(size_t)(colw + nt * 16 + ln) * HID + ks * 32 + q * 8];
            float4 lo = ((const float4*)p)[0];
            float4 hi = ((const float4*)p)[1];
            w2f[ks][nt] = (bf16x8){(bf16)lo.x, (bf16)lo.y, (bf16)lo.z, (bf16)lo.w,
                                   (bf16)hi.x, (bf16)hi.y, (bf16)hi.z, (bf16)hi.w};
        }

    f32x4 b1v[2], b2v[2], wcv[2];
    #pragma unroll
    for (int nt = 0; nt < 2; ++nt) {
        const int n4 = colw + nt * 16 + q * 4;
        b1v[nt] = *(const f32x4*)&b1[n4];
        b2v[nt] = *(const f32x4*)&b2[n4];
    }

    // ---- stage tile 0 into xs[0]; prefetch tile 1; one barrier ----
    {
        bf16x8 v0 = (bf16x8){(bf16)px[0][0].x, (bf16)px[0][0].y, (bf16)px[0][0].z, (bf16)px[0][0].w,
                             (bf16)px[0][1].x, (bf16)px[0][1].y, (bf16)px[0][1].z, (bf16)px[0][1].w};
        *(bf16x8*)&xs[0][r0_ * XS_PITCH + cc0 * 8] = v0;
        bf16x8 v1 = (bf16x8){(bf16)px[1][0].x, (bf16)px[1][0].y, (bf16)px[1][0].z, (bf16)px[1][0].w,
                             (bf16)px[1][1].x, (bf16)px[1][1].y, (bf16)px[1][1].z, (bf16)px[1][1].w};
        *(bf16x8*)&xs[0][r1_ * XS_PITCH + cc1 * 8] = v1;
    }
    {   // prefetch tile 1
        const int nrow0 = brow0 + BM;
        const float* s0 = (cc0 < 12) ? (state  + (size_t)(nrow0 + r0_) * SDIM + cc0 * 8)
                                     : (action + (size_t)(nrow0 + r0_) * ADIM + (cc0 - 12) * 8);
        px[0][0] = ((const float4*)s0)[0];
        px[0][1] = ((const float4*)s0)[1];
        const float* s1 = (cc1 < 12) ? (state  + (size_t)(nrow0 + r1_) * SDIM + cc1 * 8)
                                     : (action + (size_t)(nrow0 + r1_) * ADIM + (cc1 - 12) * 8);
        px[1][0] = ((const float4*)s1)[0];
        px[1][1] = ((const float4*)s1)[1];
    }
    __syncthreads();   // xs[0] + wcs/bcs ready

    #pragma unroll
    for (int nt = 0; nt < 2; ++nt) {
        const int n4 = colw + nt * 16 + q * 4;
        const f32x4 w0  = *(const f32x4*)&wcs[0][n4];
        const f32x4 w1v = *(const f32x4*)&wcs[1][n4];
        #pragma unroll
        for (int r = 0; r < 4; ++r) wcv[nt][r] = w0[r] + w1v[r];
    }
    const float bc = bcs;

    for (int t = 0; t < NTILES; ++t) {
        const int row0 = brow0 + t * BM;
        const int cur  = t & 1;
        const int nxt  = cur ^ 1;

        // ---- GEMM1 (transposed): D1[n][m] = W1 . x^T over this wave's 32 n ----
        f32x4 acc[4][2];   // [mt][nt]
        #pragma unroll
        for (int mt = 0; mt < 4; ++mt)
            #pragma unroll
            for (int nt = 0; nt < 2; ++nt)
                acc[mt][nt] = (f32x4){0.f, 0.f, 0.f, 0.f};

        #pragma unroll
        for (int ks = 0; ks < 4; ++ks) {
            const int k0 = ks * 32 + q * 8;
            bf16x8 bfr[4];
            #pragma unroll
            for (int mt = 0; mt < 4; ++mt)
                bfr[mt] = *(const bf16x8*)&xs[cur][(mt * 16 + ln) * XS_PITCH + k0];
            #pragma unroll
            for (int mt = 0; mt < 4; ++mt)
                #pragma unroll
                for (int nt = 0; nt < 2; ++nt)
                    acc[mt][nt] = __builtin_amdgcn_mfma_f32_16x16x32_bf16(w1f[ks][nt], bfr[mt], acc[mt][nt], 0, 0, 0);
        }

        // ---- stage NEXT tile into xs[nxt] (px vmcnt hidden by GEMM1) ----
        if (t + 1 < NTILES) {
            bf16x8 v0 = (bf16x8){(bf16)px[0][0].x, (bf16)px[0][0].y, (bf16)px[0][0].z, (bf16)px[0][0].w,
                                 (bf16)px[0][1].x, (bf16)px[0][1].y, (bf16)px[0][1].z, (bf16)px[0][1].w};
            *(bf16x8*)&xs[nxt][r0_ * XS_PITCH + cc0 * 8] = v0;
            bf16x8 v1 = (bf16x8){(bf16)px[1][0].x, (bf16)px[1][0].y, (bf16)px[1][0].z, (bf16)px[1][0].w,
                                 (bf16)px[1][1].x, (bf16)px[1][1].y, (bf16)px[1][1].z, (bf16)px[1][1].w};
            *(bf16x8*)&xs[nxt][r1_ * XS_PITCH + cc1 * 8] = v1;
        }
        if (t + 2 < NTILES) {   // prefetch tile t+2 into px
            const int nrow0 = row0 + 2 * BM;
            const float* s0 = (cc0 < 12) ? (state  + (size_t)(nrow0 + r0_) * SDIM + cc0 * 8)
                                         : (action + (size_t)(nrow0 + r0_) * ADIM + (cc0 - 12) * 8);
            px[0][0] = ((const float4*)s0)[0];
            px[0][1] = ((const float4*)s0)[1];
            const float* s1 = (cc1 < 12) ? (state  + (size_t)(nrow0 + r1_) * SDIM + cc1 * 8)
                                         : (action + (size_t)(nrow0 + r1_) * ADIM + (cc1 - 12) * 8);
            px[1][0] = ((const float4*)s1)[0];
            px[1][1] = ((const float4*)s1)[1];
        }

        // epi1: bias+relu -> h1s (ds_write_b64 per (nt,mt))
        #pragma unroll
        for (int nt = 0; nt < 2; ++nt) {
            #pragma unroll
            for (int mt = 0; mt < 4; ++mt) {
                bf16x4 v4;
                #pragma unroll
                for (int r = 0; r < 4; ++r) {
                    float v = acc[mt][nt][r] + b1v[nt][r];
                    v = v > 0.f ? v : 0.f;
                    v4[r] = (bf16)v;
                }
                *(bf16x4*)&h1s[(mt * 16 + ln) * H1_PITCH + colw + nt * 16 + q * 4] = v4;
            }
        }
        __syncthreads();   // B: h1s ready; xs[nxt] writes complete

        // ---- GEMM2 (transposed): D2[n][m] = W2 . h1^T ----
        #pragma unroll
        for (int mt = 0; mt < 4; ++mt)
            #pragma unroll
            for (int nt = 0; nt < 2; ++nt)
                acc[mt][nt] = (f32x4){0.f, 0.f, 0.f, 0.f};

        #pragma unroll
        for (int ks = 0; ks < 8; ++ks) {
            const int k0 = ks * 32 + q * 8;
            bf16x8 bfr[4];
            #pragma unroll
            for (int mt = 0; mt < 4; ++mt)
                bfr[mt] = *(const bf16x8*)&h1s[(mt * 16 + ln) * H1_PITCH + k0];
            #pragma unroll
            for (int mt = 0; mt < 4; ++mt)
                #pragma unroll
                for (int nt = 0; nt < 2; ++nt)
                    acc[mt][nt] = __builtin_amdgcn_mfma_f32_16x16x32_bf16(w2f[ks][nt], bfr[mt], acc[mt][nt], 0, 0, 0);
        }

        // epi2: bias+relu+Wc-dot in-lane; cross-lane reduce over q only
        float partial[4];
        #pragma unroll
        for (int mt = 0; mt < 4; ++mt) {
            float p = 0.f;
            #pragma unroll
            for (int nt = 0; nt < 2; ++nt)
                #pragma unroll
                for (int r = 0; r < 4; ++r) {
                    float v = acc[mt][nt][r] + b2v[nt][r];
                    v = v > 0.f ? v : 0.f;
                    p += v * wcv[nt][r];
                }
            partial[mt] = p;
        }
        #pragma unroll
        for (int mt = 0; mt < 4; ++mt) {
            partial[mt] += __shfl_xor(partial[mt], 16, 64);
            partial[mt] += __shfl_xor(partial[mt], 32, 64);
        }
        if (q == 0) {
            #pragma unroll
            for (int mt = 0; mt < 4; ++mt)
                sPart[wave][mt * 16 + ln] = partial[mt];
        }
        __syncthreads();   // C: sPart ready; h1s/xs[cur] reads drained

        if (tid < BM) {
            float v = bc;
            #pragma unroll
            for (int w = 0; w < 8; ++w) v += sPart[w][tid];
            out[row0 + tid] = v;
        }
        // next iteration's GEMM1 reads xs[nxt] (ready since barrier B);
        // epi1 overwrite of h1s is ordered after barrier C.
    }
}

extern "C" void kernel_launch(void* const* d_in, const int* in_sizes, int n_in,
                              void* d_out, int out_size, void* d_ws, size_t ws_size,
                              hipStream_t stream) {
    const float* state  = (const float*)d_in[0];
    const float* action = (const float*)d_in[1];
    const float* alphas = (const float*)d_in[2];
    const float* W1     = (const float*)d_in[3];
    const float* b1     = (const float*)d_in[4];
    const float* W2     = (const float*)d_in[5];
    const float* b2     = (const float*)d_in[6];
    const float* Wh     = (const float*)d_in[7];
    const float* bh     = (const float*)d_in[8];
    float* out = (float*)d_out;

    // d_ws unused: the 256MiB poison fills are UNCONDITIONAL (R11 proof),
    // so ws buys nothing; in-kernel prep keeps us a single launch.
    (void)d_ws; (void)ws_size;

    critic_kernel<<<B_TOTAL / (BM * NTILES), 512, 0, stream>>>(
        state, action, alphas, W1, b1, W2, b2, Wh, bh, out);
}